// Round 1
// baseline (104.820 us; speedup 1.0000x reference)
//
#include <hip/hip_runtime.h>

// out[b,c,a,j] = mean_{4x4}( images[b,c, 4*((a - W_shifts[b]) mod 56) .. +3,
//                                        4*((j - H_shifts[b]) mod 56) .. +3] )
// Gather form: one thread per output element; writes coalesced, reads are
// four float4 loads per thread (16B/lane, aligned: row stride 224*4=896B=56*16B).

__global__ __launch_bounds__(256) void ds_wrap_translate_kernel(
    const float* __restrict__ images,
    const int*   __restrict__ H_shifts,
    const int*   __restrict__ W_shifts,
    float*       __restrict__ out)
{
    constexpr int C = 3, H = 224, W = 224, h = 56, w = 56;
    constexpr int total = 128 * C * h * w;  // 1,204,224 = 4704 * 256

    int tid = blockIdx.x * blockDim.x + threadIdx.x;
    if (tid >= total) return;

    int j  = tid % w;
    int t1 = tid / w;
    int a  = t1 % h;
    int t2 = t1 / h;
    int c  = t2 % C;
    int b  = t2 / C;

    // kornia ordering: dy (height shift) = W_shifts, dx (width shift) = H_shifts
    int dy = W_shifts[b];
    int dx = H_shifts[b];

    int sa = a - dy; if (sa < 0) sa += h;   // dy in [0,h)
    int sj = j - dx; if (sj < 0) sj += w;   // dx in [0,w)

    const float* base = images + ((size_t)(b * C + c) * H + 4 * sa) * W + 4 * sj;

    float4 r0 = *(const float4*)(base);
    float4 r1 = *(const float4*)(base + W);
    float4 r2 = *(const float4*)(base + 2 * W);
    float4 r3 = *(const float4*)(base + 3 * W);

    float s = (r0.x + r0.y + r0.z + r0.w)
            + (r1.x + r1.y + r1.z + r1.w)
            + (r2.x + r2.y + r2.z + r2.w)
            + (r3.x + r3.y + r3.z + r3.w);

    out[tid] = s * (1.0f / 16.0f);
}

extern "C" void kernel_launch(void* const* d_in, const int* in_sizes, int n_in,
                              void* d_out, int out_size, void* d_ws, size_t ws_size,
                              hipStream_t stream) {
    const float* images   = (const float*)d_in[0];
    const int*   H_shifts = (const int*)d_in[1];
    const int*   W_shifts = (const int*)d_in[2];
    float*       out      = (float*)d_out;

    constexpr int total = 128 * 3 * 56 * 56;
    dim3 grid((total + 255) / 256), block(256);
    ds_wrap_translate_kernel<<<grid, block, 0, stream>>>(images, H_shifts, W_shifts, out);
}